// Round 5
// baseline (772.717 us; speedup 1.0000x reference)
//
#include <hip/hip_runtime.h>

#define EPS 1e-5f
typedef long long ll;
typedef unsigned int uint;
typedef float f32x2 __attribute__((ext_vector_type(2)));
typedef int   i32x2 __attribute__((ext_vector_type(2)));
typedef int   i32x4 __attribute__((ext_vector_type(4)));
typedef float f32x4 __attribute__((ext_vector_type(4)));

// ---- counting-sort geometry ----
// coarse bin = bucket >> 8 (256 fine buckets per bin)
// chunks of 8192 items; counts[bin][chunk], chunk dim padded to NCPAD
#define CHUNK   8192
#define NCPAD   512
#define NBMAX   2048
#define P3CAP   8192   // LDS staging capacity (int2) in p3

__device__ __forceinline__ uint bf_round(float x) {
    uint u = __float_as_uint(x);
    return (u + 0x7FFFu + ((u >> 16) & 1u)) >> 16;
}
__device__ __forceinline__ uint pack2(float a, float b) {
    return bf_round(a) | (bf_round(b) << 16);
}
__device__ __forceinline__ float unpack_lo(uint u) { return __uint_as_float(u << 16); }
__device__ __forceinline__ float unpack_hi(uint u) { return __uint_as_float(u & 0xFFFF0000u); }

// ---- nontemporal (streaming, evict-first) access helpers ----
__device__ __forceinline__ int2 nt_load_i2(const int2* p) {
    i32x2 v = __builtin_nontemporal_load((const i32x2*)p);
    int2 r; r.x = v.x; r.y = v.y; return r;
}
__device__ __forceinline__ int nt_load_i(const int* p) {
    return __builtin_nontemporal_load(p);
}
__device__ __forceinline__ float nt_load_f(const float* p) {
    return __builtin_nontemporal_load(p);
}
__device__ __forceinline__ float4 nt_load_f4(const float4* p) {
    f32x4 v = __builtin_nontemporal_load((const f32x4*)p);
    float4 r; r.x = v.x; r.y = v.y; r.z = v.z; r.w = v.w; return r;
}
__device__ __forceinline__ void nt_store_f4(float4* p, float4 v) {
    f32x4 t; t.x = v.x; t.y = v.y; t.z = v.z; t.w = v.w;
    __builtin_nontemporal_store(t, (f32x4*)p);
}

// ---- P1: blocks [0,hb) LDS-histogram coarse bins; blocks [hb,hb+tb) f32->bf16 ----
__global__ __launch_bounds__(256) void hist_conv_k(
    const int* __restrict__ rows, const int* __restrict__ cols,
    int* __restrict__ counts, int ne, int nu, int NB, int hb,
    const float* __restrict__ ue, const float* __restrict__ ie,
    uint4* __restrict__ bfout, int nuT, int totT)
{
    int b = blockIdx.x;
    if (b < hb) {
        __shared__ int hist[NBMAX];
        for (int i = threadIdx.x; i < NB; i += 256) hist[i] = 0;
        __syncthreads();
        ll base0 = (ll)b * CHUNK;
        ll items = 2LL * ne;
        int n2 = (int)min((ll)CHUNK, items - base0);
        for (int k = threadIdx.x; k < n2; k += 256) {
            ll e = base0 + k;
            int bucket = (e < ne) ? rows[e] : nu + cols[e - ne];
            atomicAdd(&hist[bucket >> 8], 1);
        }
        __syncthreads();
        for (int i = threadIdx.x; i < NB; i += 256)
            counts[(ll)i * NCPAD + b] = hist[i];
    } else {
        int t = (b - hb) * 256 + threadIdx.x;
        if (t < totT) {
            const float4* src = (t < nuT) ? (const float4*)(ue + (ll)t * 8)
                                          : (const float4*)(ie + (ll)(t - nuT) * 8);
            // streaming read of the f32 embeddings (dead after conversion)
            float4 f0 = nt_load_f4(src), f1 = nt_load_f4(src + 1);
            uint4 q;
            q.x = pack2(f0.x, f0.y); q.y = pack2(f0.z, f0.w);
            q.z = pack2(f1.x, f1.y); q.w = pack2(f1.z, f1.w);
            bfout[t] = q;   // normal store: this is L1-gather's hot table
        }
    }
}

// ---- S1: per-bin exclusive scan over chunks (2 per thread); emits bin totals ----
__global__ __launch_bounds__(256) void s1_kernel(
    const int* __restrict__ counts, int* __restrict__ base,
    int* __restrict__ binT, int nchunk)
{
    int b = blockIdx.x;
    int t = threadIdx.x;
    int i0 = 2 * t, i1 = 2 * t + 1;
    int v0 = (i0 < nchunk) ? counts[(ll)b * NCPAD + i0] : 0;
    int v1 = (i1 < nchunk) ? counts[(ll)b * NCPAD + i1] : 0;
    int s = v0 + v1;
    __shared__ int sm[256];
    sm[t] = s; __syncthreads();
    for (int off = 1; off < 256; off <<= 1) {
        int a = (t >= off) ? sm[t - off] : 0;
        __syncthreads();
        sm[t] += a;
        __syncthreads();
    }
    int excl = sm[t] - s;
    base[(ll)b * NCPAD + i0] = excl;
    base[(ll)b * NCPAD + i1] = excl + v0;
    if (t == 255) binT[b] = sm[255];
}

// ---- S2: single-block exclusive scan of bin totals -> binptr ----
__global__ __launch_bounds__(256) void s2_kernel(
    const int* __restrict__ binT, int* __restrict__ binptr,
    int* __restrict__ rowptr, int NB, int Nrow, int total)
{
    __shared__ int sm[256];
    int t = threadIdx.x;
    const int PER = NBMAX / 256; // 8
    int loc[PER]; int s = 0;
#pragma unroll
    for (int k = 0; k < PER; k++) {
        int i = t * PER + k;
        loc[k] = (i < NB) ? binT[i] : 0;
        s += loc[k];
    }
    sm[t] = s; __syncthreads();
    for (int off = 1; off < 256; off <<= 1) {
        int a = (t >= off) ? sm[t - off] : 0;
        __syncthreads();
        sm[t] += a;
        __syncthreads();
    }
    int run = sm[t] - s;
#pragma unroll
    for (int k = 0; k < PER; k++) {
        int i = t * PER + k;
        if (i < NB) binptr[i] = run;
        run += loc[k];
    }
    if (t == 0) { binptr[NB] = total; rowptr[Nrow] = total; }
}

// ---- P2: scatter 8B records into bin-major tmp via LDS cursors ----
__global__ __launch_bounds__(256) void p2_kernel(
    const int* __restrict__ rows, const int* __restrict__ cols,
    const float* __restrict__ vals,
    const int* __restrict__ base, const int* __restrict__ binptr,
    int2* __restrict__ tmp, int ne, int nu, int NB)
{
    __shared__ int cur[NBMAX];
    int c = blockIdx.x;
    for (int i = threadIdx.x; i < NB; i += 256)
        cur[i] = binptr[i] + base[(ll)i * NCPAD + c];
    __syncthreads();
    ll base0 = (ll)c * CHUNK;
    ll items = 2LL * ne;
    int n2 = (int)min((ll)CHUNK, items - base0);
    for (int k = threadIdx.x; k < n2; k += 256) {
        ll e = base0 + k;
        int bucket, src; float v;
        if (e < ne) {
            bucket = nt_load_i(rows + e); src = nt_load_i(cols + e);
            v = nt_load_f(vals + e);
        } else {
            ll e2 = e - ne;
            bucket = nu + nt_load_i(cols + e2); src = nt_load_i(rows + e2);
            v = nt_load_f(vals + e2);
        }
        int slot = atomicAdd(&cur[bucket >> 8], 1);
        // key = fine-bucket (8b) << 24 | src (src < 2^24)
        tmp[slot] = make_int2(((bucket & 255) << 24) | src, __float_as_int(v));
    }
}

// ---- P3: per-bin fine rank; single pass with LDS staging (fallback: 2-pass) ----
__global__ __launch_bounds__(256) void p3_kernel(
    const int2* __restrict__ tmp, const int* __restrict__ binptr,
    int* __restrict__ rowptr, int2* __restrict__ csr)
{
    __shared__ int hist[256];
    __shared__ int sm[256];
    __shared__ int2 stage[P3CAP];   // 64 KB
    int b = blockIdx.x;
    int t = threadIdx.x;
    int s0 = binptr[b], s1 = binptr[b + 1];
    int n = s1 - s0;
    bool inLds = (n <= P3CAP);      // wave-uniform
    hist[t] = 0; __syncthreads();
    if (inLds) {
        for (int i = t; i < n; i += 256) {
            int2 it = nt_load_i2(tmp + s0 + i);   // tmp is dead after p3
            stage[i] = it;
            atomicAdd(&hist[(uint)it.x >> 24], 1);
        }
    } else {
        for (int i = t; i < n; i += 256)
            atomicAdd(&hist[(uint)nt_load_i2(tmp + s0 + i).x >> 24], 1);
    }
    __syncthreads();
    int v = hist[t];
    sm[t] = v; __syncthreads();
    for (int off = 1; off < 256; off <<= 1) {
        int a = (t >= off) ? sm[t - off] : 0;
        __syncthreads();
        sm[t] += a;
        __syncthreads();
    }
    int excl = sm[t] - v;
    __syncthreads();
    rowptr[(b << 8) + t] = s0 + excl;   // padded rowptr: always safe
    hist[t] = excl;                      // reuse as cursor
    __syncthreads();
    if (inLds) {
        for (int i = t; i < n; i += 256) {
            int2 it = stage[i];
            int r = atomicAdd(&hist[(uint)it.x >> 24], 1);
            csr[s0 + r] = make_int2(it.x & 0xFFFFFF, it.y);   // hot: normal store
        }
    } else {
        for (int i = t; i < n; i += 256) {
            int2 it = nt_load_i2(tmp + s0 + i);
            int r = atomicAdd(&hist[(uint)it.x >> 24], 1);
            csr[s0 + r] = make_int2(it.x & 0xFFFFFF, it.y);
        }
    }
}

// ============ gather SpMM (bf16) + residual + LayerNorm ============
// 4 rows per wave, one per 16-lane sub. csr 2 ahead (NT), gather 1 ahead.
// Streaming accesses (csr, f32 output) are nontemporal so the 76.8 MB bf16
// gather table stays LLC-resident.
template<bool OUT_BF>
__global__ __launch_bounds__(256) void gather_ln_k(
    const uint4* __restrict__ srcU,  // table gathered by user rows
    const uint4* __restrict__ srcI,  // table gathered by item rows
    const uint4* __restrict__ resU, const uint4* __restrict__ resI,
    void* __restrict__ outU, void* __restrict__ outI,
    const int* __restrict__ rowptr, const int2* __restrict__ csr,
    const float* __restrict__ gamma, const float* __restrict__ beta,
    int nu, int N)
{
    int gw = blockIdx.x * 4 + (threadIdx.x >> 6);   // wave id
    if (gw * 4 >= N) return;
    int lane = threadIdx.x & 63;
    int sub  = lane >> 4;   // row slot 0..3
    int l16  = lane & 15;   // 16B chunk in row -> channels l16*8 .. +7

    int row = gw * 4 + sub;
    bool rv = row < N;
    int rowc = rv ? row : N - 1;     // clamped for pointer math only

    int start = rv ? rowptr[row]     : 0;
    int end   = rv ? rowptr[row + 1] : 0;
    int deg   = end - start;
    // wave-max degree (uniform within sub; reduce across the 4 subs)
    int md = deg;
    md = max(md, __shfl_xor(md, 16, 64));
    md = max(md, __shfl_xor(md, 32, 64));

    const uint4* tbl;
    const uint4* res;
    char* outp;
    if (rowc < nu) {
        tbl  = srcU;
        res  = resU + (ll)rowc * 16;
        outp = OUT_BF ? (char*)outU + (ll)rowc * 256
                      : (char*)outU + (ll)rowc * 512;
    } else {
        int k = rowc - nu;
        tbl  = srcI;
        res  = resI + (ll)k * 16;
        outp = OUT_BF ? (char*)outI + (ll)k * 256
                      : (char*)outI + (ll)k * 512;
    }

    f32x2 a01 = {0.f, 0.f}, a23 = {0.f, 0.f}, a45 = {0.f, 0.f}, a67 = {0.f, 0.f};

#define FMA8(q, vv) {                                                   \
        f32x2 b;                                                        \
        b[0] = unpack_lo(q.x); b[1] = unpack_hi(q.x); a01 = vv * b + a01; \
        b[0] = unpack_lo(q.y); b[1] = unpack_hi(q.y); a23 = vv * b + a23; \
        b[0] = unpack_lo(q.z); b[1] = unpack_hi(q.z); a45 = vv * b + a45; \
        b[0] = unpack_lo(q.w); b[1] = unpack_hi(q.w); a67 = vv * b + a67; }

    if (md > 0) {
        // prologue: edge 0 csr+gather in flight, edge 1 csr in flight
        int2 ec0 = nt_load_i2(csr + ((0 < deg) ? start     : 0));
        int2 ec1 = nt_load_i2(csr + ((1 < deg) ? start + 1 : 0));
        uint4 q0 = tbl[(((uint)ec0.x) << 4) + l16];
        for (int k = 0; k < md; ++k) {
            int2 ec2 = nt_load_i2(csr + (((k + 2) < deg) ? (start + k + 2) : 0));
            uint4 q1 = tbl[(((uint)ec1.x) << 4) + l16];
            float vm = (k < deg) ? __int_as_float(ec0.y) : 0.0f;
            f32x2 vv = {vm, vm};
            FMA8(q0, vv);
            ec0 = ec1; ec1 = ec2; q0 = q1;
        }
    }
#undef FMA8

    float a0 = a01[0], a1 = a01[1], a2 = a23[0], a3 = a23[1];
    float a4 = a45[0], a5 = a45[1], a6 = a67[0], a7 = a67[1];

    // residual (bf16 row; hot table data -> normal load)
    uint4 r = res[l16];
    a0 += unpack_lo(r.x); a1 += unpack_hi(r.x);
    a2 += unpack_lo(r.y); a3 += unpack_hi(r.y);
    a4 += unpack_lo(r.z); a5 += unpack_hi(r.z);
    a6 += unpack_lo(r.w); a7 += unpack_hi(r.w);

    // LN stats over the 16-lane sub (offsets < 16 stay within the sub)
    float s  = a0+a1+a2+a3+a4+a5+a6+a7;
    float ss = a0*a0+a1*a1+a2*a2+a3*a3+a4*a4+a5*a5+a6*a6+a7*a7;
#pragma unroll
    for (int off = 8; off > 0; off >>= 1) {
        s  += __shfl_xor(s, off, 64);
        ss += __shfl_xor(ss, off, 64);
    }
    float m   = s * (1.0f / 128.0f);
    float var = ss * (1.0f / 128.0f) - m * m;
    float inv = rsqrtf(var + EPS);

    float4 g0 = ((const float4*)gamma)[l16 * 2];
    float4 g1 = ((const float4*)gamma)[l16 * 2 + 1];
    float4 b0 = ((const float4*)beta)[l16 * 2];
    float4 b1 = ((const float4*)beta)[l16 * 2 + 1];
    float o0 = g0.x * (a0 - m) * inv + b0.x;
    float o1 = g0.y * (a1 - m) * inv + b0.y;
    float o2 = g0.z * (a2 - m) * inv + b0.z;
    float o3 = g0.w * (a3 - m) * inv + b0.w;
    float o4 = g1.x * (a4 - m) * inv + b1.x;
    float o5 = g1.y * (a5 - m) * inv + b1.y;
    float o6 = g1.z * (a6 - m) * inv + b1.z;
    float o7 = g1.w * (a7 - m) * inv + b1.w;

    if (rv) {
        if (OUT_BF) {
            // L1 bf16 output: NORMAL store (it is layer 2's hot gather table)
            uint4 q;
            q.x = pack2(o0, o1); q.y = pack2(o2, o3);
            q.z = pack2(o4, o5); q.w = pack2(o6, o7);
            ((uint4*)outp)[l16] = q;
        } else {
            // final f32 output: never re-read -> nontemporal
            nt_store_f4((float4*)outp + l16 * 2,     make_float4(o0, o1, o2, o3));
            nt_store_f4((float4*)outp + l16 * 2 + 1, make_float4(o4, o5, o6, o7));
        }
    }
}

extern "C" void kernel_launch(void* const* d_in, const int* in_sizes, int n_in,
                              void* d_out, int out_size, void* d_ws, size_t ws_size,
                              hipStream_t stream)
{
    const float* user_emb = (const float*)d_in[0];
    const float* item_emb = (const float*)d_in[1];
    const float* vals     = (const float*)d_in[2];
    const float* gamma    = (const float*)d_in[3];
    const float* beta     = (const float*)d_in[4];
    const int*   rows     = (const int*)d_in[5];
    const int*   cols     = (const int*)d_in[6];

    const int nu = in_sizes[0] / 128;   // 100000
    const int ni = in_sizes[1] / 128;   // 200000
    const int ne = in_sizes[2];         // 2000000
    const int N  = nu + ni;
    const int total = 2 * ne;

    float* dout   = (float*)d_out;
    float* dout_u = dout;
    float* dout_i = dout + (ll)nu * 128;

    // bf16 input tables live in d_out until layer 2 overwrites it
    uint* bf_u = (uint*)d_out;                 // nu*64 uints (25.6 MB)
    uint* bf_i = bf_u + (ll)nu * 64;           // ni*64 uints (51.2 MB)

    // ---- geometry ----
    const int NB = (N + 255) >> 8;                       // 1172 coarse bins
    const int hb = (total + CHUNK - 1) / CHUNK;          // 489 chunks (<= NCPAD)

    // ---- workspace layout (~115 MB) ----
    // tmp (32 MB int2) aliases wu/wi (76.8 MB): tmp dies after p3.
    int*  rowptr  = (int*)d_ws;                          // NB*256 ints
    int*  counts  = rowptr + (ll)NB * 256;               // NB*NCPAD
    int*  base    = counts + (ll)NB * NCPAD;             // NB*NCPAD
    int*  binT    = base + (ll)NB * NCPAD;               // NBMAX
    int*  binptr  = binT + NBMAX;                        // NBMAX (NB+1 used)
    int2* csr     = (int2*)(binptr + NBMAX);             // total int2, 32 MB
    uint* wu_out  = (uint*)(csr + total);                // nu*64, 25.6 MB
    uint* wi_out  = wu_out + (ll)nu * 64;                // ni*64, 51.2 MB
    int2* tmp     = (int2*)wu_out;                       // total int2, 32 MB (aliased)

    const int totT = (nu + ni) * 16;
    const int tb   = (totT + 255) / 256;

    // ---- CSR build: LDS-atomic counting sort ----
    hist_conv_k<<<hb + tb, 256, 0, stream>>>(rows, cols, counts, ne, nu, NB, hb,
                                             user_emb, item_emb,
                                             (uint4*)bf_u, nu * 16, totT);
    s1_kernel<<<NB, 256, 0, stream>>>(counts, base, binT, hb);
    s2_kernel<<<1, 256, 0, stream>>>(binT, binptr, rowptr, NB, N, total);
    p2_kernel<<<hb, 256, 0, stream>>>(rows, cols, vals, base, binptr, tmp, ne, nu, NB);
    p3_kernel<<<NB, 256, 0, stream>>>(tmp, binptr, rowptr, csr);

    const int gblocks = (N + 15) / 16;   // 16 rows per block (4 waves x 4 rows)

    // ---- layer 1 ----
    gather_ln_k<true><<<gblocks, 256, 0, stream>>>(
        (const uint4*)bf_i, (const uint4*)bf_u,
        (const uint4*)bf_u, (const uint4*)bf_i,
        wu_out, wi_out,
        rowptr, csr, gamma, beta, nu, N);

    // ---- layer 2 ----
    gather_ln_k<false><<<gblocks, 256, 0, stream>>>(
        (const uint4*)wi_out, (const uint4*)wu_out,
        (const uint4*)wu_out, (const uint4*)wi_out,
        dout_u, dout_i,
        rowptr, csr, gamma, beta, nu, N);
}

// Round 6
// 671.187 us; speedup vs baseline: 1.1513x; 1.1513x over previous
//
#include <hip/hip_runtime.h>

#define EPS 1e-5f
typedef long long ll;
typedef unsigned int uint;
typedef float f32x2 __attribute__((ext_vector_type(2)));

// ---- counting-sort geometry ----
// coarse bin = bucket >> 8 (256 fine buckets per bin)
// chunks of 8192 items; counts[bin][chunk], chunk dim padded to NCPAD
#define CHUNK   8192
#define NCPAD   512
#define NBMAX   2048
#define P3CAP   8192   // LDS staging capacity (int2) in p3

__device__ __forceinline__ uint bf_round(float x) {
    uint u = __float_as_uint(x);
    return (u + 0x7FFFu + ((u >> 16) & 1u)) >> 16;
}
__device__ __forceinline__ uint pack2(float a, float b) {
    return bf_round(a) | (bf_round(b) << 16);
}
__device__ __forceinline__ float unpack_lo(uint u) { return __uint_as_float(u << 16); }
__device__ __forceinline__ float unpack_hi(uint u) { return __uint_as_float(u & 0xFFFF0000u); }

// ---- P1: blocks [0,hb) LDS-histogram coarse bins; blocks [hb,hb+tb) f32->bf16 ----
__global__ __launch_bounds__(256) void hist_conv_k(
    const int* __restrict__ rows, const int* __restrict__ cols,
    int* __restrict__ counts, int ne, int nu, int NB, int hb,
    const float* __restrict__ ue, const float* __restrict__ ie,
    uint4* __restrict__ bfout, int nuT, int totT)
{
    int b = blockIdx.x;
    if (b < hb) {
        __shared__ int hist[NBMAX];
        for (int i = threadIdx.x; i < NB; i += 256) hist[i] = 0;
        __syncthreads();
        ll base0 = (ll)b * CHUNK;
        ll items = 2LL * ne;
        int n2 = (int)min((ll)CHUNK, items - base0);
        for (int k = threadIdx.x; k < n2; k += 256) {
            ll e = base0 + k;
            int bucket = (e < ne) ? rows[e] : nu + cols[e - ne];
            atomicAdd(&hist[bucket >> 8], 1);
        }
        __syncthreads();
        for (int i = threadIdx.x; i < NB; i += 256)
            counts[(ll)i * NCPAD + b] = hist[i];
    } else {
        int t = (b - hb) * 256 + threadIdx.x;
        if (t < totT) {
            const float4* src = (t < nuT) ? (const float4*)(ue + (ll)t * 8)
                                          : (const float4*)(ie + (ll)(t - nuT) * 8);
            float4 f0 = src[0], f1 = src[1];
            uint4 q;
            q.x = pack2(f0.x, f0.y); q.y = pack2(f0.z, f0.w);
            q.z = pack2(f1.x, f1.y); q.w = pack2(f1.z, f1.w);
            bfout[t] = q;
        }
    }
}

// ---- S1: per-bin exclusive scan over chunks (2 per thread); emits bin totals ----
__global__ __launch_bounds__(256) void s1_kernel(
    const int* __restrict__ counts, int* __restrict__ base,
    int* __restrict__ binT, int nchunk)
{
    int b = blockIdx.x;
    int t = threadIdx.x;
    int i0 = 2 * t, i1 = 2 * t + 1;
    int v0 = (i0 < nchunk) ? counts[(ll)b * NCPAD + i0] : 0;
    int v1 = (i1 < nchunk) ? counts[(ll)b * NCPAD + i1] : 0;
    int s = v0 + v1;
    __shared__ int sm[256];
    sm[t] = s; __syncthreads();
    for (int off = 1; off < 256; off <<= 1) {
        int a = (t >= off) ? sm[t - off] : 0;
        __syncthreads();
        sm[t] += a;
        __syncthreads();
    }
    int excl = sm[t] - s;
    base[(ll)b * NCPAD + i0] = excl;
    base[(ll)b * NCPAD + i1] = excl + v0;
    if (t == 255) binT[b] = sm[255];
}

// ---- S2: single-block exclusive scan of bin totals -> binptr ----
__global__ __launch_bounds__(256) void s2_kernel(
    const int* __restrict__ binT, int* __restrict__ binptr,
    int* __restrict__ rowptr, int NB, int Nrow, int total)
{
    __shared__ int sm[256];
    int t = threadIdx.x;
    const int PER = NBMAX / 256; // 8
    int loc[PER]; int s = 0;
#pragma unroll
    for (int k = 0; k < PER; k++) {
        int i = t * PER + k;
        loc[k] = (i < NB) ? binT[i] : 0;
        s += loc[k];
    }
    sm[t] = s; __syncthreads();
    for (int off = 1; off < 256; off <<= 1) {
        int a = (t >= off) ? sm[t - off] : 0;
        __syncthreads();
        sm[t] += a;
        __syncthreads();
    }
    int run = sm[t] - s;
#pragma unroll
    for (int k = 0; k < PER; k++) {
        int i = t * PER + k;
        if (i < NB) binptr[i] = run;
        run += loc[k];
    }
    if (t == 0) { binptr[NB] = total; rowptr[Nrow] = total; }
}

// ---- P2: scatter 8B records into bin-major tmp via LDS cursors ----
__global__ __launch_bounds__(256) void p2_kernel(
    const int* __restrict__ rows, const int* __restrict__ cols,
    const float* __restrict__ vals,
    const int* __restrict__ base, const int* __restrict__ binptr,
    int2* __restrict__ tmp, int ne, int nu, int NB)
{
    __shared__ int cur[NBMAX];
    int c = blockIdx.x;
    for (int i = threadIdx.x; i < NB; i += 256)
        cur[i] = binptr[i] + base[(ll)i * NCPAD + c];
    __syncthreads();
    ll base0 = (ll)c * CHUNK;
    ll items = 2LL * ne;
    int n2 = (int)min((ll)CHUNK, items - base0);
    for (int k = threadIdx.x; k < n2; k += 256) {
        ll e = base0 + k;
        int bucket, src; float v;
        if (e < ne) { bucket = rows[e]; src = cols[e]; v = vals[e]; }
        else        { ll e2 = e - ne; bucket = nu + cols[e2]; src = rows[e2]; v = vals[e2]; }
        int slot = atomicAdd(&cur[bucket >> 8], 1);
        // key = fine-bucket (8b) << 24 | src (src < 2^24)
        tmp[slot] = make_int2(((bucket & 255) << 24) | src, __float_as_int(v));
    }
}

// ---- P3: per-bin fine rank; single pass with LDS staging (fallback: 2-pass) ----
__global__ __launch_bounds__(256) void p3_kernel(
    const int2* __restrict__ tmp, const int* __restrict__ binptr,
    int* __restrict__ rowptr, int2* __restrict__ csr)
{
    __shared__ int hist[256];
    __shared__ int sm[256];
    __shared__ int2 stage[P3CAP];   // 64 KB
    int b = blockIdx.x;
    int t = threadIdx.x;
    int s0 = binptr[b], s1 = binptr[b + 1];
    int n = s1 - s0;
    bool inLds = (n <= P3CAP);      // wave-uniform
    hist[t] = 0; __syncthreads();
    if (inLds) {
        for (int i = t; i < n; i += 256) {
            int2 it = tmp[s0 + i];
            stage[i] = it;
            atomicAdd(&hist[(uint)it.x >> 24], 1);
        }
    } else {
        for (int i = t; i < n; i += 256)
            atomicAdd(&hist[(uint)tmp[s0 + i].x >> 24], 1);
    }
    __syncthreads();
    int v = hist[t];
    sm[t] = v; __syncthreads();
    for (int off = 1; off < 256; off <<= 1) {
        int a = (t >= off) ? sm[t - off] : 0;
        __syncthreads();
        sm[t] += a;
        __syncthreads();
    }
    int excl = sm[t] - v;
    __syncthreads();
    rowptr[(b << 8) + t] = s0 + excl;   // padded rowptr: always safe
    hist[t] = excl;                      // reuse as cursor
    __syncthreads();
    if (inLds) {
        for (int i = t; i < n; i += 256) {
            int2 it = stage[i];
            int r = atomicAdd(&hist[(uint)it.x >> 24], 1);
            csr[s0 + r] = make_int2(it.x & 0xFFFFFF, it.y);
        }
    } else {
        for (int i = t; i < n; i += 256) {
            int2 it = tmp[s0 + i];
            int r = atomicAdd(&hist[(uint)it.x >> 24], 1);
            csr[s0 + r] = make_int2(it.x & 0xFFFFFF, it.y);
        }
    }
}

// ============ gather SpMM (bf16) + residual + LayerNorm ============
// 4 rows per wave, one per 16-lane sub. 2 edges per iteration per sub:
// 2 table gathers + 4 csr entries in flight; even/odd accumulator banks
// break the FMA dependence chain.
template<bool OUT_BF>
__global__ __launch_bounds__(256) void gather_ln_k(
    const uint4* __restrict__ srcU,  // table gathered by user rows
    const uint4* __restrict__ srcI,  // table gathered by item rows
    const uint4* __restrict__ resU, const uint4* __restrict__ resI,
    void* __restrict__ outU, void* __restrict__ outI,
    const int* __restrict__ rowptr, const int2* __restrict__ csr,
    const float* __restrict__ gamma, const float* __restrict__ beta,
    int nu, int N)
{
    int gw = blockIdx.x * 4 + (threadIdx.x >> 6);   // wave id
    if (gw * 4 >= N) return;
    int lane = threadIdx.x & 63;
    int sub  = lane >> 4;   // row slot 0..3
    int l16  = lane & 15;   // 16B chunk in row -> channels l16*8 .. +7

    int row = gw * 4 + sub;
    bool rv = row < N;
    int rowc = rv ? row : N - 1;     // clamped for pointer math only

    int start = rv ? rowptr[row]     : 0;
    int end   = rv ? rowptr[row + 1] : 0;
    int deg   = end - start;
    // wave-max degree (uniform within sub; reduce across the 4 subs)
    int md = deg;
    md = max(md, __shfl_xor(md, 16, 64));
    md = max(md, __shfl_xor(md, 32, 64));

    const uint4* tbl;
    const uint4* res;
    char* outp;
    if (rowc < nu) {
        tbl  = srcU;
        res  = resU + (ll)rowc * 16;
        outp = OUT_BF ? (char*)outU + (ll)rowc * 256
                      : (char*)outU + (ll)rowc * 512;
    } else {
        int k = rowc - nu;
        tbl  = srcI;
        res  = resI + (ll)k * 16;
        outp = OUT_BF ? (char*)outI + (ll)k * 256
                      : (char*)outI + (ll)k * 512;
    }

    f32x2 e01 = {0.f,0.f}, e23 = {0.f,0.f}, e45 = {0.f,0.f}, e67 = {0.f,0.f};
    f32x2 o01 = {0.f,0.f}, o23 = {0.f,0.f}, o45 = {0.f,0.f}, o67 = {0.f,0.f};

#define FMA8(q, vv, A, B, C, D) {                                       \
        f32x2 b_;                                                       \
        b_[0] = unpack_lo(q.x); b_[1] = unpack_hi(q.x); A = vv * b_ + A; \
        b_[0] = unpack_lo(q.y); b_[1] = unpack_hi(q.y); B = vv * b_ + B; \
        b_[0] = unpack_lo(q.z); b_[1] = unpack_hi(q.z); C = vv * b_ + C; \
        b_[0] = unpack_lo(q.w); b_[1] = unpack_hi(q.w); D = vv * b_ + D; }

    if (md > 0) {
        // prologue: edges 0..3 csr in flight, edges 0..1 gathers in flight
        int2 ec0 = csr[(0 < deg) ? start     : 0];
        int2 ec1 = csr[(1 < deg) ? start + 1 : 0];
        int2 ec2 = csr[(2 < deg) ? start + 2 : 0];
        int2 ec3 = csr[(3 < deg) ? start + 3 : 0];
        uint4 q0 = tbl[(((uint)ec0.x) << 4) + l16];
        uint4 q1 = tbl[(((uint)ec1.x) << 4) + l16];
        for (int k = 0; k < md; k += 2) {
            int2 ec4 = csr[((k + 4) < deg) ? (start + k + 4) : 0];
            int2 ec5 = csr[((k + 5) < deg) ? (start + k + 5) : 0];
            uint4 q2 = tbl[(((uint)ec2.x) << 4) + l16];
            uint4 q3 = tbl[(((uint)ec3.x) << 4) + l16];
            float v0 = (k < deg)       ? __int_as_float(ec0.y) : 0.0f;
            float v1 = ((k + 1) < deg) ? __int_as_float(ec1.y) : 0.0f;
            f32x2 vv0 = {v0, v0}, vv1 = {v1, v1};
            FMA8(q0, vv0, e01, e23, e45, e67);
            FMA8(q1, vv1, o01, o23, o45, o67);
            ec0 = ec2; ec1 = ec3; ec2 = ec4; ec3 = ec5;
            q0 = q2; q1 = q3;
        }
    }
#undef FMA8

    f32x2 a01 = e01 + o01, a23 = e23 + o23, a45 = e45 + o45, a67 = e67 + o67;
    float a0 = a01[0], a1 = a01[1], a2 = a23[0], a3 = a23[1];
    float a4 = a45[0], a5 = a45[1], a6 = a67[0], a7 = a67[1];

    // residual (bf16 row; 4 consecutive rows -> 1 KB contiguous per wave)
    uint4 r = res[l16];
    a0 += unpack_lo(r.x); a1 += unpack_hi(r.x);
    a2 += unpack_lo(r.y); a3 += unpack_hi(r.y);
    a4 += unpack_lo(r.z); a5 += unpack_hi(r.z);
    a6 += unpack_lo(r.w); a7 += unpack_hi(r.w);

    // LN stats over the 16-lane sub (offsets < 16 stay within the sub)
    float s  = a0+a1+a2+a3+a4+a5+a6+a7;
    float ss = a0*a0+a1*a1+a2*a2+a3*a3+a4*a4+a5*a5+a6*a6+a7*a7;
#pragma unroll
    for (int off = 8; off > 0; off >>= 1) {
        s  += __shfl_xor(s, off, 64);
        ss += __shfl_xor(ss, off, 64);
    }
    float m   = s * (1.0f / 128.0f);
    float var = ss * (1.0f / 128.0f) - m * m;
    float inv = rsqrtf(var + EPS);

    float4 g0 = ((const float4*)gamma)[l16 * 2];
    float4 g1 = ((const float4*)gamma)[l16 * 2 + 1];
    float4 b0 = ((const float4*)beta)[l16 * 2];
    float4 b1 = ((const float4*)beta)[l16 * 2 + 1];
    float o0 = g0.x * (a0 - m) * inv + b0.x;
    float o1 = g0.y * (a1 - m) * inv + b0.y;
    float o2 = g0.z * (a2 - m) * inv + b0.z;
    float o3 = g0.w * (a3 - m) * inv + b0.w;
    float o4 = g1.x * (a4 - m) * inv + b1.x;
    float o5 = g1.y * (a5 - m) * inv + b1.y;
    float o6 = g1.z * (a6 - m) * inv + b1.z;
    float o7 = g1.w * (a7 - m) * inv + b1.w;

    if (rv) {
        if (OUT_BF) {
            uint4 q;
            q.x = pack2(o0, o1); q.y = pack2(o2, o3);
            q.z = pack2(o4, o5); q.w = pack2(o6, o7);
            ((uint4*)outp)[l16] = q;
        } else {
            ((float4*)outp)[l16 * 2]     = make_float4(o0, o1, o2, o3);
            ((float4*)outp)[l16 * 2 + 1] = make_float4(o4, o5, o6, o7);
        }
    }
}

extern "C" void kernel_launch(void* const* d_in, const int* in_sizes, int n_in,
                              void* d_out, int out_size, void* d_ws, size_t ws_size,
                              hipStream_t stream)
{
    const float* user_emb = (const float*)d_in[0];
    const float* item_emb = (const float*)d_in[1];
    const float* vals     = (const float*)d_in[2];
    const float* gamma    = (const float*)d_in[3];
    const float* beta     = (const float*)d_in[4];
    const int*   rows     = (const int*)d_in[5];
    const int*   cols     = (const int*)d_in[6];

    const int nu = in_sizes[0] / 128;   // 100000
    const int ni = in_sizes[1] / 128;   // 200000
    const int ne = in_sizes[2];         // 2000000
    const int N  = nu + ni;
    const int total = 2 * ne;

    float* dout   = (float*)d_out;
    float* dout_u = dout;
    float* dout_i = dout + (ll)nu * 128;

    // bf16 input tables live in d_out until layer 2 overwrites it
    uint* bf_u = (uint*)d_out;                 // nu*64 uints (25.6 MB)
    uint* bf_i = bf_u + (ll)nu * 64;           // ni*64 uints (51.2 MB)

    // ---- geometry ----
    const int NB = (N + 255) >> 8;                       // 1172 coarse bins
    const int hb = (total + CHUNK - 1) / CHUNK;          // 489 chunks (<= NCPAD)

    // ---- workspace layout (~115 MB) ----
    // tmp (32 MB int2) aliases wu/wi (76.8 MB): tmp dies after p3.
    int*  rowptr  = (int*)d_ws;                          // NB*256 ints
    int*  counts  = rowptr + (ll)NB * 256;               // NB*NCPAD
    int*  base    = counts + (ll)NB * NCPAD;             // NB*NCPAD
    int*  binT    = base + (ll)NB * NCPAD;               // NBMAX
    int*  binptr  = binT + NBMAX;                        // NBMAX (NB+1 used)
    int2* csr     = (int2*)(binptr + NBMAX);             // total int2, 32 MB
    uint* wu_out  = (uint*)(csr + total);                // nu*64, 25.6 MB
    uint* wi_out  = wu_out + (ll)nu * 64;                // ni*64, 51.2 MB
    int2* tmp     = (int2*)wu_out;                       // total int2, 32 MB (aliased)

    const int totT = (nu + ni) * 16;
    const int tb   = (totT + 255) / 256;

    // ---- CSR build: LDS-atomic counting sort ----
    hist_conv_k<<<hb + tb, 256, 0, stream>>>(rows, cols, counts, ne, nu, NB, hb,
                                             user_emb, item_emb,
                                             (uint4*)bf_u, nu * 16, totT);
    s1_kernel<<<NB, 256, 0, stream>>>(counts, base, binT, hb);
    s2_kernel<<<1, 256, 0, stream>>>(binT, binptr, rowptr, NB, N, total);
    p2_kernel<<<hb, 256, 0, stream>>>(rows, cols, vals, base, binptr, tmp, ne, nu, NB);
    p3_kernel<<<NB, 256, 0, stream>>>(tmp, binptr, rowptr, csr);

    const int gblocks = (N + 15) / 16;   // 16 rows per block (4 waves x 4 rows)

    // ---- layer 1 ----
    gather_ln_k<true><<<gblocks, 256, 0, stream>>>(
        (const uint4*)bf_i, (const uint4*)bf_u,
        (const uint4*)bf_u, (const uint4*)bf_i,
        wu_out, wi_out,
        rowptr, csr, gamma, beta, nu, N);

    // ---- layer 2 ----
    gather_ln_k<false><<<gblocks, 256, 0, stream>>>(
        (const uint4*)wi_out, (const uint4*)wu_out,
        (const uint4*)wu_out, (const uint4*)wi_out,
        dout_u, dout_i,
        rowptr, csr, gamma, beta, nu, N);
}